// Round 1
// baseline (191.382 us; speedup 1.0000x reference)
//
#include <hip/hip_runtime.h>
#include <math.h>

#define NN 4096
#define EE 262144
#define NGRAPHS 8
#define DMODEL 64
#define NOUT 4

__device__ __forceinline__ float lrelu(float x, float s){ return x > 0.f ? x : s*x; }
__device__ __forceinline__ float pick4(float4 v, int h){
  return h==0 ? v.x : (h==1 ? v.y : (h==2 ? v.z : v.w));
}

// ---------------- CSR build ----------------
__global__ void k_init(int* deg, int* ctr, float* pooled, float* gcnt){
  int t = blockIdx.x*256 + threadIdx.x;
  if (t < NN){ deg[t]=0; ctr[t]=0; }
  if (t < NGRAPHS*DMODEL) pooled[t]=0.f;
  if (t < NGRAPHS) gcnt[t]=0.f;
}

__global__ void k_count(const int* __restrict__ ei, const int* __restrict__ batch,
                        int* deg, float* gcnt){
  int t = blockIdx.x*blockDim.x + threadIdx.x;
  if (t < EE) atomicAdd(&deg[ei[EE + t]], 1);
  if (t < NN) atomicAdd(&gcnt[batch[t]], 1.f);
}

__global__ void k_scan(const int* __restrict__ deg, int* off){
  __shared__ int part[256];
  int t = threadIdx.x;
  int base = t*16;
  int vals[16]; int s = 0;
  #pragma unroll
  for (int i=0;i<16;i++){ vals[i]=s; s += deg[base+i]; }
  part[t] = s;
  __syncthreads();
  for (int d=1; d<256; d<<=1){
    int v = (t>=d) ? part[t-d] : 0;
    __syncthreads();
    part[t] += v;
    __syncthreads();
  }
  int excl = (t==0) ? 0 : part[t-1];
  #pragma unroll
  for (int i=0;i<16;i++) off[base+i] = excl + vals[i];
  if (t==255) off[NN] = part[255];
}

__global__ void k_scatter(const int* __restrict__ ei, const int* __restrict__ off,
                          int* ctr, int* esrc){
  int e = blockIdx.x*blockDim.x + threadIdx.x;
  if (e >= EE) return;
  int d = ei[EE + e];
  int pos = off[d] + atomicAdd(&ctr[d], 1);
  esrc[pos] = ei[e];   // store src id directly (no eperm indirection)
}

// -------- feature_fc + GAT1 linear + attention sums --------
// wave per node; lane owns 4 channels of the 256-wide h1 row
__global__ void k_node1(const float* __restrict__ x, const float* __restrict__ Wf,
                        const float* __restrict__ bf, const float* __restrict__ W1,
                        const float* __restrict__ as1, const float* __restrict__ ad1,
                        float* __restrict__ h1, float* __restrict__ asum1,
                        float* __restrict__ adsum1){
  int wid = threadIdx.x >> 6, lane = threadIdx.x & 63;
  int n = blockIdx.x*4 + wid;
  float emb[4];
  #pragma unroll
  for (int j=0;j<4;j++) emb[j] = bf[j];
  #pragma unroll
  for (int k=0;k<8;k++){
    float xv = x[n*8+k];
    #pragma unroll
    for (int j=0;j<4;j++) emb[j] += xv * Wf[k*4+j];
  }
  int c0 = lane*4;
  float4 hv = make_float4(0.f,0.f,0.f,0.f);
  #pragma unroll
  for (int k=0;k<4;k++){
    float4 w = *(const float4*)&W1[k*256 + c0];
    hv.x += emb[k]*w.x; hv.y += emb[k]*w.y; hv.z += emb[k]*w.z; hv.w += emb[k]*w.w;
  }
  *(float4*)&h1[n*256 + c0] = hv;
  int h = lane >> 4;
  int idx = c0 & 63;
  float4 as = *(const float4*)&as1[h*64 + idx];
  float4 ad = *(const float4*)&ad1[h*64 + idx];
  float ps = hv.x*as.x + hv.y*as.y + hv.z*as.z + hv.w*as.w;
  float pd = hv.x*ad.x + hv.y*ad.y + hv.z*ad.z + hv.w*ad.w;
  #pragma unroll
  for (int m=1;m<16;m<<=1){ ps += __shfl_xor(ps,m,64); pd += __shfl_xor(pd,m,64); }
  if ((lane & 15) == 0){ asum1[n*4+h] = ps; adsum1[n*4+h] = pd; }
}

// -------- GAT1 softmax aggregation: wave per dst node --------
__global__ void k_gat1(const int* __restrict__ offp, const int* __restrict__ esrc,
                       const float* __restrict__ h1, const float* __restrict__ asum1,
                       const float* __restrict__ adsum1, const float* __restrict__ b1,
                       float* __restrict__ g1){
  int wid = threadIdx.x>>6, lane = threadIdx.x&63;
  int n = blockIdx.x*4 + wid;
  int start = offp[n];
  int deg = offp[n+1] - start;
  int h = lane >> 4;
  float4 adst = *(const float4*)&adsum1[n*4];
  // Phase A: per-head max of asum[src] (LeakyReLU monotone -> defer it)
  float4 mx = make_float4(-INFINITY,-INFINITY,-INFINITY,-INFINITY);
  for (int k=lane;k<deg;k+=64){
    int j = esrc[start+k];
    float4 a = *(const float4*)&asum1[j*4];
    mx.x=fmaxf(mx.x,a.x); mx.y=fmaxf(mx.y,a.y); mx.z=fmaxf(mx.z,a.z); mx.w=fmaxf(mx.w,a.w);
  }
  #pragma unroll
  for (int m=1;m<64;m<<=1){
    mx.x=fmaxf(mx.x,__shfl_xor(mx.x,m,64));
    mx.y=fmaxf(mx.y,__shfl_xor(mx.y,m,64));
    mx.z=fmaxf(mx.z,__shfl_xor(mx.z,m,64));
    mx.w=fmaxf(mx.w,__shfl_xor(mx.w,m,64));
  }
  float4 mh;
  mh.x = lrelu(mx.x+adst.x,0.2f); mh.y = lrelu(mx.y+adst.y,0.2f);
  mh.z = lrelu(mx.z+adst.z,0.2f); mh.w = lrelu(mx.w+adst.w,0.2f);
  // Phase B: denominator
  float4 den = make_float4(0.f,0.f,0.f,0.f);
  for (int k=lane;k<deg;k+=64){
    int j = esrc[start+k];
    float4 a = *(const float4*)&asum1[j*4];
    den.x += expf(lrelu(a.x+adst.x,0.2f)-mh.x);
    den.y += expf(lrelu(a.y+adst.y,0.2f)-mh.y);
    den.z += expf(lrelu(a.z+adst.z,0.2f)-mh.z);
    den.w += expf(lrelu(a.w+adst.w,0.2f)-mh.w);
  }
  #pragma unroll
  for (int m=1;m<64;m<<=1){
    den.x += __shfl_xor(den.x,m,64);
    den.y += __shfl_xor(den.y,m,64);
    den.z += __shfl_xor(den.z,m,64);
    den.w += __shfl_xor(den.w,m,64);
  }
  // Phase C: weighted gather, lane owns channels [4*lane, 4*lane+4)
  float adsth = pick4(adst,h);
  float mhl   = pick4(mh,h);
  float invl  = 1.f/(pick4(den,h)+1e-16f);
  float4 acc = make_float4(0.f,0.f,0.f,0.f);
  int c0 = lane*4;
  #pragma unroll 4
  for (int k=0;k<deg;k++){
    int j = esrc[start+k];
    float aj = asum1[j*4+h];
    float al = expf(lrelu(aj+adsth,0.2f)-mhl)*invl;
    float4 hvv = *(const float4*)&h1[j*256 + c0];
    acc.x += al*hvv.x; acc.y += al*hvv.y; acc.z += al*hvv.z; acc.w += al*hvv.w;
  }
  float4 bb = *(const float4*)&b1[c0];
  float4 o;
  o.x = lrelu(acc.x+bb.x, 0.01f);
  o.y = lrelu(acc.y+bb.y, 0.01f);
  o.z = lrelu(acc.z+bb.z, 0.01f);
  o.w = lrelu(acc.w+bb.w, 0.01f);
  *(float4*)&g1[n*256 + c0] = o;
}

// -------- GAT2 linear (g1 @ W2) + attention sums; W2 staged in LDS --------
__global__ void k_node2(const float* __restrict__ g1, const float* __restrict__ W2,
                        const float* __restrict__ as2, const float* __restrict__ ad2,
                        float* __restrict__ h2, float* __restrict__ asum2,
                        float* __restrict__ adsum2){
  __shared__ float w2s[256*64];   // 64 KB
  int t = threadIdx.x;
  for (int i=t; i<256*64; i+=256) w2s[i] = W2[i];
  __syncthreads();
  int wid = t>>6, lane = t&63;
  for (int r=0;r<4;r++){
    int n = blockIdx.x*16 + r*4 + wid;
    float acc = 0.f;
    #pragma unroll 8
    for (int k=0;k<256;k++) acc += g1[n*256+k] * w2s[k*64+lane];
    h2[n*64+lane] = acc;
    int hh = lane>>4, idx = lane&15;
    float ps = acc * as2[hh*16+idx];
    float pd = acc * ad2[hh*16+idx];
    #pragma unroll
    for (int m=1;m<16;m<<=1){ ps += __shfl_xor(ps,m,64); pd += __shfl_xor(pd,m,64); }
    if (idx == 0){ asum2[n*4+hh] = ps; adsum2[n*4+hh] = pd; }
  }
}

// -------- GAT2 aggregation + decoder FFN + pooled accumulation --------
__global__ void k_gat2(const int* __restrict__ offp, const int* __restrict__ esrc,
                       const float* __restrict__ h2, const float* __restrict__ asum2,
                       const float* __restrict__ adsum2, const float* __restrict__ b2,
                       const float* __restrict__ dW1, const float* __restrict__ db1,
                       const float* __restrict__ dW2, const float* __restrict__ db2,
                       const int* __restrict__ batch, float* pooled){
  __shared__ float sh[4][64];
  __shared__ float shh[4][32];
  int wid = threadIdx.x>>6, lane = threadIdx.x&63;
  int n = blockIdx.x*4 + wid;
  int start = offp[n];
  int deg = offp[n+1] - start;
  int h = lane >> 4;
  float4 adst = *(const float4*)&adsum2[n*4];
  float4 mx = make_float4(-INFINITY,-INFINITY,-INFINITY,-INFINITY);
  for (int k=lane;k<deg;k+=64){
    int j = esrc[start+k];
    float4 a = *(const float4*)&asum2[j*4];
    mx.x=fmaxf(mx.x,a.x); mx.y=fmaxf(mx.y,a.y); mx.z=fmaxf(mx.z,a.z); mx.w=fmaxf(mx.w,a.w);
  }
  #pragma unroll
  for (int m=1;m<64;m<<=1){
    mx.x=fmaxf(mx.x,__shfl_xor(mx.x,m,64));
    mx.y=fmaxf(mx.y,__shfl_xor(mx.y,m,64));
    mx.z=fmaxf(mx.z,__shfl_xor(mx.z,m,64));
    mx.w=fmaxf(mx.w,__shfl_xor(mx.w,m,64));
  }
  float4 mh;
  mh.x = lrelu(mx.x+adst.x,0.2f); mh.y = lrelu(mx.y+adst.y,0.2f);
  mh.z = lrelu(mx.z+adst.z,0.2f); mh.w = lrelu(mx.w+adst.w,0.2f);
  float4 den = make_float4(0.f,0.f,0.f,0.f);
  for (int k=lane;k<deg;k+=64){
    int j = esrc[start+k];
    float4 a = *(const float4*)&asum2[j*4];
    den.x += expf(lrelu(a.x+adst.x,0.2f)-mh.x);
    den.y += expf(lrelu(a.y+adst.y,0.2f)-mh.y);
    den.z += expf(lrelu(a.z+adst.z,0.2f)-mh.z);
    den.w += expf(lrelu(a.w+adst.w,0.2f)-mh.w);
  }
  #pragma unroll
  for (int m=1;m<64;m<<=1){
    den.x += __shfl_xor(den.x,m,64);
    den.y += __shfl_xor(den.y,m,64);
    den.z += __shfl_xor(den.z,m,64);
    den.w += __shfl_xor(den.w,m,64);
  }
  float adsth = pick4(adst,h);
  float mhl   = pick4(mh,h);
  float invl  = 1.f/(pick4(den,h)+1e-16f);
  float acc = 0.f;
  #pragma unroll 4
  for (int k=0;k<deg;k++){
    int j = esrc[start+k];
    float aj = asum2[j*4+h];
    float al = expf(lrelu(aj+adsth,0.2f)-mhl)*invl;
    acc += al * h2[j*64+lane];
  }
  float g2v = lrelu(acc + b2[lane], 0.01f);
  sh[wid][lane] = g2v;
  __syncthreads();
  // decoder FFN (encoder branch is dead code in the reference)
  int m = lane & 31;
  float a2 = db1[m];
  #pragma unroll
  for (int k=0;k<64;k++) a2 += sh[wid][k] * dW1[k*32+m];
  if (lane < 32) shh[wid][m] = fmaxf(a2, 0.f);
  __syncthreads();
  float tv = db2[lane];
  #pragma unroll
  for (int k=0;k<32;k++) tv += shh[wid][k] * dW2[k*64+lane];
  tv = fmaxf(tv, 0.f);
  atomicAdd(&pooled[batch[n]*64 + lane], tv);
}

// -------- mean-pool finalize + fc --------
__global__ void k_final(const float* __restrict__ pooled, const float* __restrict__ gcnt,
                        const float* __restrict__ W_fc, const float* __restrict__ b_fc,
                        float* __restrict__ out){
  __shared__ float pm[NGRAPHS][DMODEL];
  int t = threadIdx.x;           // 512 threads
  int g = t>>6, c = t&63;
  pm[g][c] = pooled[g*64+c] / fmaxf(gcnt[g], 1.f);
  __syncthreads();
  if (t < NGRAPHS*NOUT){
    int gg = t>>2, o = t&3;
    float a = b_fc[o];
    #pragma unroll
    for (int k=0;k<64;k++) a += pm[gg][k] * W_fc[k*4+o];
    out[gg*4+o] = a;
  }
}

extern "C" void kernel_launch(void* const* d_in, const int* in_sizes, int n_in,
                              void* d_out, int out_size, void* d_ws, size_t ws_size,
                              hipStream_t stream){
  const float* x      = (const float*)d_in[0];
  const int*   ei     = (const int*)  d_in[1];
  const int*   batch  = (const int*)  d_in[2];
  const float* W_feat = (const float*)d_in[3];
  const float* b_feat = (const float*)d_in[4];
  const float* W1     = (const float*)d_in[5];
  const float* as1    = (const float*)d_in[6];
  const float* ad1    = (const float*)d_in[7];
  const float* b1     = (const float*)d_in[8];
  const float* W2     = (const float*)d_in[9];
  const float* as2    = (const float*)d_in[10];
  const float* ad2    = (const float*)d_in[11];
  const float* b2     = (const float*)d_in[12];
  // d_in[13..16] = encoder FFN weights: dead code in reference, unused
  const float* dW1    = (const float*)d_in[17];
  const float* db1    = (const float*)d_in[18];
  const float* dW2    = (const float*)d_in[19];
  const float* db2    = (const float*)d_in[20];
  const float* W_fc   = (const float*)d_in[21];
  const float* b_fc   = (const float*)d_in[22];
  float* out = (float*)d_out;

  char* ws = (char*)d_ws;
  float* h1     = (float*)(ws + 0);         // 4 MB
  float* g1     = (float*)(ws + 4194304);   // 4 MB
  float* h2     = (float*)(ws + 8388608);   // 1 MB
  float* asum1  = (float*)(ws + 9437184);   // 64 KB
  float* adsum1 = (float*)(ws + 9502720);
  float* asum2  = (float*)(ws + 9568256);
  float* adsum2 = (float*)(ws + 9633792);
  int*   deg    = (int*)  (ws + 9699328);   // 16 KB
  int*   ctr    = (int*)  (ws + 9715712);
  int*   offp   = (int*)  (ws + 9732096);   // (N+1) ints, padded
  int*   esrc   = (int*)  (ws + 9748736);   // 1 MB
  float* pooled = (float*)(ws + 10797312);  // 8*64
  float* gcnt   = (float*)(ws + 10799360);  // 8

  k_init   <<<16,        256, 0, stream>>>(deg, ctr, pooled, gcnt);
  k_count  <<<EE/256,    256, 0, stream>>>(ei, batch, deg, gcnt);
  k_scan   <<<1,         256, 0, stream>>>(deg, offp);
  k_scatter<<<EE/256,    256, 0, stream>>>(ei, offp, ctr, esrc);
  k_node1  <<<NN/4,      256, 0, stream>>>(x, W_feat, b_feat, W1, as1, ad1, h1, asum1, adsum1);
  k_gat1   <<<NN/4,      256, 0, stream>>>(offp, esrc, h1, asum1, adsum1, b1, g1);
  k_node2  <<<256,       256, 0, stream>>>(g1, W2, as2, ad2, h2, asum2, adsum2);
  k_gat2   <<<NN/4,      256, 0, stream>>>(offp, esrc, h2, asum2, adsum2, b2,
                                           dW1, db1, dW2, db2, batch, pooled);
  k_final  <<<1,         512, 0, stream>>>(pooled, gcnt, W_fc, b_fc, out);
}

// Round 2
// 140.359 us; speedup vs baseline: 1.3635x; 1.3635x over previous
//
#include <hip/hip_runtime.h>
#include <math.h>

#define NN 4096
#define EE 262144
#define NCHUNK 64
#define CHSZ 4096      // EE / NCHUNK
#define NGRAPHS 8
#define DMODEL 64
#define NOUT 4

__device__ __forceinline__ float lrelu(float x, float s){ return x > 0.f ? x : s*x; }
__device__ __forceinline__ float pick4(float4 v, int h){
  return h==0 ? v.x : (h==1 ? v.y : (h==2 ? v.z : v.w));
}

// ---------------- CSR build (no global atomics) ----------------
// per-chunk LDS histogram of dst
__global__ void k_hist(const int* __restrict__ ei, int* __restrict__ hist){
  __shared__ int sh[NN];
  int t = threadIdx.x, c = blockIdx.x;
  for (int v=t; v<NN; v+=256) sh[v]=0;
  __syncthreads();
  int base = c*CHSZ;
  #pragma unroll
  for (int i=0;i<16;i++){
    int d = ei[EE + base + i*256 + t];
    atomicAdd(&sh[d],1);            // LDS atomic (CU-local, fast)
  }
  __syncthreads();
  for (int v=t; v<NN; v+=256) hist[c*NN+v]=sh[v];
}

// column-wise exclusive scan over chunks (in place) + total degree
__global__ void k_colscan(int* __restrict__ hist, int* __restrict__ deg){
  int v = blockIdx.x*256 + threadIdx.x;
  int s = 0;
  for (int c=0;c<NCHUNK;c++){
    int h = hist[c*NN+v];
    hist[c*NN+v] = s;
    s += h;
  }
  deg[v] = s;
}

// block-wide scan of deg -> off; plus graph boundaries from sorted batch
__global__ void k_scan(const int* __restrict__ deg, int* __restrict__ off,
                       const int* __restrict__ batch, int* __restrict__ gstart){
  __shared__ int part[256];
  int t = threadIdx.x;
  int base = t*16;
  int vals[16]; int s = 0;
  #pragma unroll
  for (int i=0;i<16;i++){ vals[i]=s; s += deg[base+i]; }
  part[t] = s;
  __syncthreads();
  for (int d=1; d<256; d<<=1){
    int v = (t>=d) ? part[t-d] : 0;
    __syncthreads();
    part[t] += v;
    __syncthreads();
  }
  int excl = (t==0) ? 0 : part[t-1];
  #pragma unroll
  for (int i=0;i<16;i++) off[base+i] = excl + vals[i];
  if (t==255) off[NN] = part[255];
  if (t < NGRAPHS+1){
    int lo=0, hi=NN;
    while (lo<hi){ int mid=(lo+hi)>>1; if (batch[mid] < t) lo=mid+1; else hi=mid; }
    gstart[t]=lo;
  }
}

// scatter src ids into CSR slots; slot ranks via LDS atomics only
__global__ void k_scatter(const int* __restrict__ ei, const int* __restrict__ off,
                          const int* __restrict__ hist, int* __restrict__ esrc){
  __shared__ int sbase[NN];
  int t = threadIdx.x, c = blockIdx.x;
  for (int v=t; v<NN; v+=256) sbase[v] = off[v] + hist[c*NN+v];
  __syncthreads();
  int base = c*CHSZ;
  #pragma unroll
  for (int i=0;i<16;i++){
    int e = base + i*256 + t;
    int d = ei[EE+e], sr = ei[e];
    int pos = atomicAdd(&sbase[d],1);   // LDS atomic
    esrc[pos] = sr;
  }
}

// -------- feature_fc + GAT1 linear + attention sums --------
__global__ void k_node1(const float* __restrict__ x, const float* __restrict__ Wf,
                        const float* __restrict__ bf, const float* __restrict__ W1,
                        const float* __restrict__ as1, const float* __restrict__ ad1,
                        float* __restrict__ h1, float* __restrict__ asum1,
                        float* __restrict__ adsum1){
  int wid = threadIdx.x >> 6, lane = threadIdx.x & 63;
  int n = blockIdx.x*4 + wid;
  float emb[4];
  #pragma unroll
  for (int j=0;j<4;j++) emb[j] = bf[j];
  #pragma unroll
  for (int k=0;k<8;k++){
    float xv = x[n*8+k];
    #pragma unroll
    for (int j=0;j<4;j++) emb[j] += xv * Wf[k*4+j];
  }
  int c0 = lane*4;
  float4 hv = make_float4(0.f,0.f,0.f,0.f);
  #pragma unroll
  for (int k=0;k<4;k++){
    float4 w = *(const float4*)&W1[k*256 + c0];
    hv.x += emb[k]*w.x; hv.y += emb[k]*w.y; hv.z += emb[k]*w.z; hv.w += emb[k]*w.w;
  }
  *(float4*)&h1[n*256 + c0] = hv;
  int h = lane >> 4;
  int idx = c0 & 63;
  float4 as = *(const float4*)&as1[h*64 + idx];
  float4 ad = *(const float4*)&ad1[h*64 + idx];
  float ps = hv.x*as.x + hv.y*as.y + hv.z*as.z + hv.w*as.w;
  float pd = hv.x*ad.x + hv.y*ad.y + hv.z*ad.z + hv.w*ad.w;
  #pragma unroll
  for (int m=1;m<16;m<<=1){ ps += __shfl_xor(ps,m,64); pd += __shfl_xor(pd,m,64); }
  if ((lane & 15) == 0){ asum1[n*4+h] = ps; adsum1[n*4+h] = pd; }
}

// -------- GAT1 softmax aggregation: wave per dst node --------
__global__ void k_gat1(const int* __restrict__ offp, const int* __restrict__ esrc,
                       const float* __restrict__ h1, const float* __restrict__ asum1,
                       const float* __restrict__ adsum1, const float* __restrict__ b1,
                       float* __restrict__ g1){
  int wid = threadIdx.x>>6, lane = threadIdx.x&63;
  int n = blockIdx.x*4 + wid;
  int start = offp[n];
  int deg = offp[n+1] - start;
  int h = lane >> 4;
  float4 adst = *(const float4*)&adsum1[n*4];
  float4 mx = make_float4(-INFINITY,-INFINITY,-INFINITY,-INFINITY);
  for (int k=lane;k<deg;k+=64){
    int j = esrc[start+k];
    float4 a = *(const float4*)&asum1[j*4];
    mx.x=fmaxf(mx.x,a.x); mx.y=fmaxf(mx.y,a.y); mx.z=fmaxf(mx.z,a.z); mx.w=fmaxf(mx.w,a.w);
  }
  #pragma unroll
  for (int m=1;m<64;m<<=1){
    mx.x=fmaxf(mx.x,__shfl_xor(mx.x,m,64));
    mx.y=fmaxf(mx.y,__shfl_xor(mx.y,m,64));
    mx.z=fmaxf(mx.z,__shfl_xor(mx.z,m,64));
    mx.w=fmaxf(mx.w,__shfl_xor(mx.w,m,64));
  }
  float4 mh;
  mh.x = lrelu(mx.x+adst.x,0.2f); mh.y = lrelu(mx.y+adst.y,0.2f);
  mh.z = lrelu(mx.z+adst.z,0.2f); mh.w = lrelu(mx.w+adst.w,0.2f);
  float4 den = make_float4(0.f,0.f,0.f,0.f);
  for (int k=lane;k<deg;k+=64){
    int j = esrc[start+k];
    float4 a = *(const float4*)&asum1[j*4];
    den.x += expf(lrelu(a.x+adst.x,0.2f)-mh.x);
    den.y += expf(lrelu(a.y+adst.y,0.2f)-mh.y);
    den.z += expf(lrelu(a.z+adst.z,0.2f)-mh.z);
    den.w += expf(lrelu(a.w+adst.w,0.2f)-mh.w);
  }
  #pragma unroll
  for (int m=1;m<64;m<<=1){
    den.x += __shfl_xor(den.x,m,64);
    den.y += __shfl_xor(den.y,m,64);
    den.z += __shfl_xor(den.z,m,64);
    den.w += __shfl_xor(den.w,m,64);
  }
  float adsth = pick4(adst,h);
  float mhl   = pick4(mh,h);
  float invl  = 1.f/(pick4(den,h)+1e-16f);
  float4 acc = make_float4(0.f,0.f,0.f,0.f);
  int c0 = lane*4;
  #pragma unroll 4
  for (int k=0;k<deg;k++){
    int j = esrc[start+k];
    float aj = asum1[j*4+h];
    float al = expf(lrelu(aj+adsth,0.2f)-mhl)*invl;
    float4 hvv = *(const float4*)&h1[j*256 + c0];
    acc.x += al*hvv.x; acc.y += al*hvv.y; acc.z += al*hvv.z; acc.w += al*hvv.w;
  }
  float4 bb = *(const float4*)&b1[c0];
  float4 o;
  o.x = lrelu(acc.x+bb.x, 0.01f);
  o.y = lrelu(acc.y+bb.y, 0.01f);
  o.z = lrelu(acc.z+bb.z, 0.01f);
  o.w = lrelu(acc.w+bb.w, 0.01f);
  *(float4*)&g1[n*256 + c0] = o;
}

// -------- GAT2 linear (g1 @ W2) + attention sums; W2 staged in LDS --------
__global__ void k_node2(const float* __restrict__ g1, const float* __restrict__ W2,
                        const float* __restrict__ as2, const float* __restrict__ ad2,
                        float* __restrict__ h2, float* __restrict__ asum2,
                        float* __restrict__ adsum2){
  __shared__ float w2s[256*64];   // 64 KB
  int t = threadIdx.x;
  for (int i=t; i<256*64; i+=256) w2s[i] = W2[i];
  __syncthreads();
  int wid = t>>6, lane = t&63;
  for (int r=0;r<4;r++){
    int n = blockIdx.x*16 + r*4 + wid;
    float acc = 0.f;
    #pragma unroll 8
    for (int k=0;k<256;k++) acc += g1[n*256+k] * w2s[k*64+lane];
    h2[n*64+lane] = acc;
    int hh = lane>>4, idx = lane&15;
    float ps = acc * as2[hh*16+idx];
    float pd = acc * ad2[hh*16+idx];
    #pragma unroll
    for (int m=1;m<16;m<<=1){ ps += __shfl_xor(ps,m,64); pd += __shfl_xor(pd,m,64); }
    if (idx == 0){ asum2[n*4+hh] = ps; adsum2[n*4+hh] = pd; }
  }
}

// -------- GAT2 aggregation + decoder FFN -> per-node t --------
__global__ void k_gat2(const int* __restrict__ offp, const int* __restrict__ esrc,
                       const float* __restrict__ h2, const float* __restrict__ asum2,
                       const float* __restrict__ adsum2, const float* __restrict__ b2,
                       const float* __restrict__ dW1, const float* __restrict__ db1,
                       const float* __restrict__ dW2, const float* __restrict__ db2,
                       float* __restrict__ tbuf){
  __shared__ float sh[4][64];
  __shared__ float shh[4][32];
  int wid = threadIdx.x>>6, lane = threadIdx.x&63;
  int n = blockIdx.x*4 + wid;
  int start = offp[n];
  int deg = offp[n+1] - start;
  int h = lane >> 4;
  float4 adst = *(const float4*)&adsum2[n*4];
  float4 mx = make_float4(-INFINITY,-INFINITY,-INFINITY,-INFINITY);
  for (int k=lane;k<deg;k+=64){
    int j = esrc[start+k];
    float4 a = *(const float4*)&asum2[j*4];
    mx.x=fmaxf(mx.x,a.x); mx.y=fmaxf(mx.y,a.y); mx.z=fmaxf(mx.z,a.z); mx.w=fmaxf(mx.w,a.w);
  }
  #pragma unroll
  for (int m=1;m<64;m<<=1){
    mx.x=fmaxf(mx.x,__shfl_xor(mx.x,m,64));
    mx.y=fmaxf(mx.y,__shfl_xor(mx.y,m,64));
    mx.z=fmaxf(mx.z,__shfl_xor(mx.z,m,64));
    mx.w=fmaxf(mx.w,__shfl_xor(mx.w,m,64));
  }
  float4 mh;
  mh.x = lrelu(mx.x+adst.x,0.2f); mh.y = lrelu(mx.y+adst.y,0.2f);
  mh.z = lrelu(mx.z+adst.z,0.2f); mh.w = lrelu(mx.w+adst.w,0.2f);
  float4 den = make_float4(0.f,0.f,0.f,0.f);
  for (int k=lane;k<deg;k+=64){
    int j = esrc[start+k];
    float4 a = *(const float4*)&asum2[j*4];
    den.x += expf(lrelu(a.x+adst.x,0.2f)-mh.x);
    den.y += expf(lrelu(a.y+adst.y,0.2f)-mh.y);
    den.z += expf(lrelu(a.z+adst.z,0.2f)-mh.z);
    den.w += expf(lrelu(a.w+adst.w,0.2f)-mh.w);
  }
  #pragma unroll
  for (int m=1;m<64;m<<=1){
    den.x += __shfl_xor(den.x,m,64);
    den.y += __shfl_xor(den.y,m,64);
    den.z += __shfl_xor(den.z,m,64);
    den.w += __shfl_xor(den.w,m,64);
  }
  float adsth = pick4(adst,h);
  float mhl   = pick4(mh,h);
  float invl  = 1.f/(pick4(den,h)+1e-16f);
  float acc = 0.f;
  #pragma unroll 4
  for (int k=0;k<deg;k++){
    int j = esrc[start+k];
    float aj = asum2[j*4+h];
    float al = expf(lrelu(aj+adsth,0.2f)-mhl)*invl;
    acc += al * h2[j*64+lane];
  }
  float g2v = lrelu(acc + b2[lane], 0.01f);
  sh[wid][lane] = g2v;
  __syncthreads();
  int m = lane & 31;
  float a2 = db1[m];
  #pragma unroll
  for (int k=0;k<64;k++) a2 += sh[wid][k] * dW1[k*32+m];
  if (lane < 32) shh[wid][m] = fmaxf(a2, 0.f);
  __syncthreads();
  float tv = db2[lane];
  #pragma unroll
  for (int k=0;k<32;k++) tv += shh[wid][k] * dW2[k*64+lane];
  tbuf[n*64 + lane] = fmaxf(tv, 0.f);
}

// -------- segmented mean over sorted batch + final fc (one block/graph) ------
__global__ void k_pool(const float* __restrict__ tbuf, const int* __restrict__ gstart,
                       const float* __restrict__ W_fc, const float* __restrict__ b_fc,
                       float* __restrict__ out){
  __shared__ float part[4][64];
  __shared__ float pm[64];
  int t = threadIdx.x, w = t>>6, lane = t&63, g = blockIdx.x;
  int s0 = gstart[g], e0 = gstart[g+1];
  float sum = 0.f;
  for (int n=s0+w; n<e0; n+=4) sum += tbuf[n*64 + lane];
  part[w][lane] = sum;
  __syncthreads();
  if (w==0){
    float tot = part[0][lane]+part[1][lane]+part[2][lane]+part[3][lane];
    pm[lane] = tot / fmaxf((float)(e0-s0), 1.f);
  }
  __syncthreads();
  if (t < NOUT){
    float a = b_fc[t];
    #pragma unroll
    for (int k=0;k<64;k++) a += pm[k]*W_fc[k*4+t];
    out[g*4+t] = a;
  }
}

extern "C" void kernel_launch(void* const* d_in, const int* in_sizes, int n_in,
                              void* d_out, int out_size, void* d_ws, size_t ws_size,
                              hipStream_t stream){
  const float* x      = (const float*)d_in[0];
  const int*   ei     = (const int*)  d_in[1];
  const int*   batch  = (const int*)  d_in[2];
  const float* W_feat = (const float*)d_in[3];
  const float* b_feat = (const float*)d_in[4];
  const float* W1     = (const float*)d_in[5];
  const float* as1    = (const float*)d_in[6];
  const float* ad1    = (const float*)d_in[7];
  const float* b1     = (const float*)d_in[8];
  const float* W2     = (const float*)d_in[9];
  const float* as2    = (const float*)d_in[10];
  const float* ad2    = (const float*)d_in[11];
  const float* b2     = (const float*)d_in[12];
  // d_in[13..16] = encoder FFN weights: dead code in reference, unused
  const float* dW1    = (const float*)d_in[17];
  const float* db1    = (const float*)d_in[18];
  const float* dW2    = (const float*)d_in[19];
  const float* db2    = (const float*)d_in[20];
  const float* W_fc   = (const float*)d_in[21];
  const float* b_fc   = (const float*)d_in[22];
  float* out = (float*)d_out;

  char* ws = (char*)d_ws;
  float* h1     = (float*)(ws + 0);          // 4 MB
  float* g1     = (float*)(ws + 4194304);    // 4 MB
  float* h2     = (float*)(ws + 8388608);    // 1 MB
  float* tbuf   = (float*)(ws + 9437184);    // 1 MB
  int*   hist   = (int*)  (ws + 10485760);   // 1 MB (64 x 4096)
  int*   esrc   = (int*)  (ws + 11534336);   // 1 MB
  float* asum1  = (float*)(ws + 12582912);   // 64 KB each
  float* adsum1 = (float*)(ws + 12648448);
  float* asum2  = (float*)(ws + 12713984);
  float* adsum2 = (float*)(ws + 12779520);
  int*   deg    = (int*)  (ws + 12845056);   // 16 KB
  int*   offp   = (int*)  (ws + 12861440);   // N+1 ints
  int*   gstart = (int*)  (ws + 12877888);   // 9 ints

  k_hist   <<<NCHUNK,  256, 0, stream>>>(ei, hist);
  k_colscan<<<16,      256, 0, stream>>>(hist, deg);
  k_scan   <<<1,       256, 0, stream>>>(deg, offp, batch, gstart);
  k_scatter<<<NCHUNK,  256, 0, stream>>>(ei, offp, hist, esrc);
  k_node1  <<<NN/4,    256, 0, stream>>>(x, W_feat, b_feat, W1, as1, ad1, h1, asum1, adsum1);
  k_gat1   <<<NN/4,    256, 0, stream>>>(offp, esrc, h1, asum1, adsum1, b1, g1);
  k_node2  <<<256,     256, 0, stream>>>(g1, W2, as2, ad2, h2, asum2, adsum2);
  k_gat2   <<<NN/4,    256, 0, stream>>>(offp, esrc, h2, asum2, adsum2, b2,
                                         dW1, db1, dW2, db2, tbuf);
  k_pool   <<<NGRAPHS, 256, 0, stream>>>(tbuf, gstart, W_fc, b_fc, out);
}